// Round 1
// 145.549 us; speedup vs baseline: 1.0373x; 1.0373x over previous
//
#include <hip/hip_runtime.h>

namespace {

constexpr int B = 16;
constexpr int C = 1024;
constexpr int BC = B * C;                          // 16384
constexpr long long BCC = (long long)B * C * C;    // 16777216
constexpr float EPS  = 1e-12f;
constexpr float TINY = 1e-9f;
constexpr int TI = 8;                              // rows per block
// grid = BC / TI = 2048 blocks, 256 threads each (8 blocks/CU)

using f32x4 = __attribute__((ext_vector_type(4))) float;

// Factorized single-kernel formulation:
//   exp(l_j - u_i) = exp(l_j) * exp(-u_i)   etc.
// Per-block: per-thread j-tables (4 j's each) + 4 per-batch sums reduced once.
// Per-row: closed-form S_l, S_u, SA_l, SB_l from batch sums; only the
// division-coupled sums (sum a_u, sum a_u*l_d) need a block reduction.
__global__ __launch_bounds__(256) void bounded_softmax_kernel(
    const float* __restrict__ lower,
    const float* __restrict__ upper,
    float* __restrict__ out)
{
    const int tid = threadIdx.x;
    constexpr int rowsPerBatch = C / TI;           // 128
    const int b  = blockIdx.x / rowsPerBatch;
    const int i0 = (blockIdx.x % rowsPerBatch) * TI;

    const float* __restrict__ lrow = lower + b * C;
    const float* __restrict__ urow = upper + b * C;

    // ---- per-thread j tables (j = tid*4 + k) ----
    const f32x4 lj4 = *reinterpret_cast<const f32x4*>(lrow + tid * 4);
    const f32x4 uj4 = *reinterpret_cast<const f32x4*>(urow + tid * 4);
    float lk[4], wk[4], El[4], Eu[4], Em[4];
    float s0 = 0.f, s1 = 0.f, s2 = 0.f, s3 = 0.f;  // sum El, Eu, Em, m*Em
    #pragma unroll
    for (int k = 0; k < 4; ++k) {
        const float lj = lj4[k];
        const float uj = uj4[k];
        lk[k] = lj;
        wk[k] = uj - lj;
        El[k] = __expf(lj);
        Eu[k] = __expf(uj);
        const float mk = 0.5f * (lj + uj);
        Em[k] = __expf(mk);
        s0 += El[k]; s1 += Eu[k]; s2 += Em[k]; s3 += mk * Em[k];
    }

    // ---- block-reduce the 4 batch sums (once) ----
    __shared__ float red0[4][4];
    __shared__ float bs[4];
    __shared__ float red[2][4][2];                 // [row parity][wave][2]
    const int lane = tid & 63;
    const int wid  = tid >> 6;
    #pragma unroll
    for (int o = 32; o > 0; o >>= 1) {
        s0 += __shfl_down(s0, o);
        s1 += __shfl_down(s1, o);
        s2 += __shfl_down(s2, o);
        s3 += __shfl_down(s3, o);
    }
    if (lane == 0) {
        red0[wid][0] = s0; red0[wid][1] = s1;
        red0[wid][2] = s2; red0[wid][3] = s3;
    }
    __syncthreads();
    if (tid < 4)
        bs[tid] = red0[0][tid] + red0[1][tid] + red0[2][tid] + red0[3][tid];
    __syncthreads();
    const float SEl = bs[0], SEu = bs[1], SEm = bs[2], SmEm = bs[3];

    // ---- row loop ----
    for (int r = 0; r < TI; ++r) {
        const int i = i0 + r;
        const float l_i = lrow[i];                 // uniform -> scalar load
        const float u_i = urow[i];
        const float w_i = u_i - l_i;
        const float m_i = 0.5f * (l_i + u_i);
        const float e_li = __expf(-l_i);
        const float e_ui = __expf(-u_i);
        const float e_mi = __expf(-m_i);
        const float ewp  = __expf(w_i);            // exp(+w_i)
        const float ewn  = __expf(-w_i);           // exp(-w_i)

        // closed-form row sums (diagonal excluded analytically)
        const float S_l  = fmaf(e_ui, SEl, -ewn);
        const float S_u  = fmaf(e_li, SEu, -ewp);
        const float SA_l = fmaf(e_mi, SEm, -1.0f);
        const float SB_l = SA_l - e_mi * SmEm + m_i * e_mi * SEm;

        // per-element secant slopes a_u; reduce sum(a_u) and sum(a_u*l_d)
        float au[4];
        float ra = 0.f, rb = 0.f;
        #pragma unroll
        for (int k = 0; k < 4; ++k) {
            const float eu    = Eu[k] * e_li;
            const float el    = El[k] * e_ui;
            const float denom = wk[k] + w_i;
            float a = (eu - el) * __builtin_amdgcn_rcpf(denom + EPS);
            a = (fabsf(denom) < TINY) ? eu : a;
            au[k] = a;
            const float l_d = lk[k] - u_i;
            ra += a;
            rb = fmaf(a, l_d, rb);
        }
        #pragma unroll
        for (int o = 32; o > 0; o >>= 1) {
            ra += __shfl_down(ra, o);
            rb += __shfl_down(rb, o);
        }
        const int p = r & 1;
        if (lane == 0) { red[p][wid][0] = ra; red[p][wid][1] = rb; }
        __syncthreads();
        const float sa_full = red[p][0][0] + red[p][1][0] + red[p][2][0] + red[p][3][0];
        const float sb_full = red[p][0][1] + red[p][1][1] + red[p][2][1] + red[p][3][1];

        // subtract the diagonal term (same arithmetic as the in-loop formula)
        const float dden = w_i + w_i;
        float a_d = (ewp - ewn) * __builtin_amdgcn_rcpf(dden + EPS);
        a_d = (fabsf(dden) < TINY) ? ewp : a_d;
        const float SA_u  = sa_full - a_d;
        const float SBu2  = sb_full + a_d * w_i;   // minus a_d * (-w_i)
        const float SB_u  = S_l - SBu2;            // sum b_u = sum el - sum a_u*l_d

        // g(S) = 1/(1+S) relaxations (precise, once per row)
        const float g_l = 1.0f / (1.0f + S_l);
        const float g_u = 1.0f / (1.0f + S_u);
        const float dg  = S_u - S_l;
        float m_u = (g_u - g_l) / (dg + EPS);
        m_u = (fabsf(dg) < TINY) ? (-g_u * g_u) : m_u;
        const float c_u = g_l - m_u * S_l;
        const float m_l = -g_u * g_u;
        const float c_l = g_u - m_l * S_u;

        const int row = b * C + i;
        float* __restrict__ lower_coef = out + 2 * BC + (long long)row * C;
        float* __restrict__ upper_coef = out + 2 * BC + BCC + (long long)row * C;

        const float Kl = m_l * e_mi;
        const float dl = -m_l * SA_l;              // diagonal of lower coef
        const float du = -m_u * SA_u;              // diagonal of upper coef
        f32x4 lv, uv;
        #pragma unroll
        for (int k = 0; k < 4; ++k) {
            const int j = tid * 4 + k;
            lv[k] = (j == i) ? dl : Kl * Em[k];
            uv[k] = (j == i) ? du : m_u * au[k];
        }
        __builtin_nontemporal_store(lv, reinterpret_cast<f32x4*>(lower_coef + tid * 4));
        __builtin_nontemporal_store(uv, reinterpret_cast<f32x4*>(upper_coef + tid * 4));

        if (tid == 0) {
            out[row]                         = fminf(fmaxf(g_u, 0.f), 1.f); // soft_lower
            out[BC + row]                    = fminf(fmaxf(g_l, 0.f), 1.f); // soft_upper
            out[2 * BC + 2 * BCC + row]      = fmaf(m_l, SB_l, c_l);        // lower bias
            out[2 * BC + 2 * BCC + BC + row] = fmaf(m_u, SB_u, c_u);        // upper bias
        }
    }
}

} // namespace

extern "C" void kernel_launch(void* const* d_in, const int* in_sizes, int n_in,
                              void* d_out, int out_size, void* d_ws, size_t ws_size,
                              hipStream_t stream) {
    const float* lower = (const float*)d_in[0];
    const float* upper = (const float*)d_in[1];
    float* out = (float*)d_out;
    bounded_softmax_kernel<<<dim3(BC / TI), dim3(256), 0, stream>>>(lower, upper, out);
}

// Round 2
// 138.079 us; speedup vs baseline: 1.0934x; 1.0541x over previous
//
#include <hip/hip_runtime.h>

namespace {

constexpr int B = 16;
constexpr int C = 1024;
constexpr int BC = B * C;                          // 16384
constexpr long long BCC = (long long)B * C * C;    // 16777216
constexpr float EPS  = 1e-12f;
constexpr float TINY = 1e-9f;
constexpr int TI = 8;                              // rows per block (4 waves x 2 rows)
// grid = BC / TI = 2048 blocks, 256 threads (8 blocks/CU)

using f32x4 = __attribute__((ext_vector_type(4))) float;

// Wave-autonomous formulation: exp tables in LDS (one barrier total), then each
// wave owns whole rows: wave-local butterfly reduction (no LDS, no syncthreads),
// row scalars, and immediate streaming stores. Closed forms for S_l, S_u, SA_l,
// SB_l from 4 per-batch sums; only sum(a_u), sum(a_u*l_j) reduced per row.
__global__ __launch_bounds__(256) void bounded_softmax_kernel(
    const float* __restrict__ lower,
    const float* __restrict__ upper,
    float* __restrict__ out)
{
    const int tid  = threadIdx.x;
    const int lane = tid & 63;
    const int wid  = tid >> 6;
    constexpr int rowsPerBatch = C / TI;           // 128
    const int b  = blockIdx.x / rowsPerBatch;
    const int i0 = (blockIdx.x % rowsPerBatch) * TI;

    const float* __restrict__ lrow = lower + b * C;
    const float* __restrict__ urow = upper + b * C;

    __shared__ float sEl[C], sEu[C], sWk[C], sEm[C];   // 16 KB
    __shared__ float red0[4][4];

    // ---- table build: j = tid*4 + k ----
    const f32x4 lj4 = *reinterpret_cast<const f32x4*>(lrow + tid * 4);
    const f32x4 uj4 = *reinterpret_cast<const f32x4*>(urow + tid * 4);
    f32x4 tEl, tEu, tWk, tEm;
    float s0 = 0.f, s1 = 0.f, s2 = 0.f, s3 = 0.f;  // sum El, Eu, Em, m*Em
    #pragma unroll
    for (int k = 0; k < 4; ++k) {
        const float lj = lj4[k];
        const float uj = uj4[k];
        const float El = __expf(lj);
        const float Eu = __expf(uj);
        const float mk = 0.5f * (lj + uj);
        const float Em = __expf(mk);
        tEl[k] = El; tEu[k] = Eu; tWk[k] = uj - lj; tEm[k] = Em;
        s0 += El; s1 += Eu; s2 += Em; s3 += mk * Em;
    }
    *reinterpret_cast<f32x4*>(&sEl[tid * 4]) = tEl;
    *reinterpret_cast<f32x4*>(&sEu[tid * 4]) = tEu;
    *reinterpret_cast<f32x4*>(&sWk[tid * 4]) = tWk;
    *reinterpret_cast<f32x4*>(&sEm[tid * 4]) = tEm;
    #pragma unroll
    for (int o = 32; o > 0; o >>= 1) {
        s0 += __shfl_down(s0, o);
        s1 += __shfl_down(s1, o);
        s2 += __shfl_down(s2, o);
        s3 += __shfl_down(s3, o);
    }
    if (lane == 0) {
        red0[wid][0] = s0; red0[wid][1] = s1;
        red0[wid][2] = s2; red0[wid][3] = s3;
    }
    __syncthreads();                               // the ONLY barrier
    const float SEl  = red0[0][0] + red0[1][0] + red0[2][0] + red0[3][0];
    const float SEu  = red0[0][1] + red0[1][1] + red0[2][1] + red0[3][1];
    const float SEm  = red0[0][2] + red0[1][2] + red0[2][2] + red0[3][2];
    const float SmEm = red0[0][3] + red0[1][3] + red0[2][3] + red0[3][3];

    // ---- wave-autonomous rows: wave wid handles rows i0+wid, i0+wid+4 ----
    #pragma unroll
    for (int r = 0; r < 2; ++r) {
        const int i = i0 + wid + 4 * r;
        const float l_i = lrow[i];                 // broadcast load
        const float u_i = urow[i];
        const float w_i = u_i - l_i;
        const float m_i = 0.5f * (l_i + u_i);
        const float e_li = __expf(-l_i);
        const float e_ui = __expf(-u_i);
        const float e_mi = __expf(-m_i);
        const float ewp  = __expf(w_i);
        const float ewn  = __expf(-w_i);

        // per-element secant slopes; accumulate sum(a), sum(a*l_j) over ALL j
        float a[16];
        float ra = 0.f, rc = 0.f;
        #pragma unroll
        for (int q = 0; q < 4; ++q) {
            const int jb = q * 256 + lane * 4;
            const f32x4 El4 = *reinterpret_cast<const f32x4*>(&sEl[jb]);
            const f32x4 Eu4 = *reinterpret_cast<const f32x4*>(&sEu[jb]);
            const f32x4 Wk4 = *reinterpret_cast<const f32x4*>(&sWk[jb]);
            const f32x4 Lj4 = *reinterpret_cast<const f32x4*>(lrow + jb); // L1/L2 hot
            #pragma unroll
            for (int k = 0; k < 4; ++k) {
                const float eu    = Eu4[k] * e_li;
                const float el    = El4[k] * e_ui;
                const float denom = Wk4[k] + w_i;
                float av = (eu - el) * __builtin_amdgcn_rcpf(denom + EPS);
                av = (fabsf(denom) < TINY) ? eu : av;
                a[q * 4 + k] = av;
                ra += av;
                rc = fmaf(av, Lj4[k], rc);
            }
        }
        // wave butterfly reduce: every lane ends with the totals
        #pragma unroll
        for (int o = 1; o < 64; o <<= 1) {
            ra += __shfl_xor(ra, o);
            rc += __shfl_xor(rc, o);
        }

        // closed-form row sums + diagonal exclusion
        const float S_l  = fmaf(e_ui, SEl, -ewn);
        const float S_u  = fmaf(e_li, SEu, -ewp);
        const float SA_l = fmaf(e_mi, SEm, -1.0f);
        const float SB_l = SA_l - e_mi * SmEm + m_i * e_mi * SEm;

        const float dden = w_i + w_i;
        float a_d = (ewp - ewn) * __builtin_amdgcn_rcpf(dden + EPS);
        a_d = (fabsf(dden) < TINY) ? ewp : a_d;
        const float SA_u = ra - a_d;
        const float rb_full = rc - u_i * ra;       // sum a*(l_j - u_i) incl diag
        const float SBu2 = rb_full + a_d * w_i;    // exclude diag (l_d = -w_i)
        const float SB_u = S_l - SBu2;

        // g(S) = 1/(1+S) relaxations (precise, once per row)
        const float g_l = 1.0f / (1.0f + S_l);
        const float g_u = 1.0f / (1.0f + S_u);
        const float dg  = S_u - S_l;
        float m_u = (g_u - g_l) / (dg + EPS);
        m_u = (fabsf(dg) < TINY) ? (-g_u * g_u) : m_u;
        const float c_u = g_l - m_u * S_l;
        const float m_l = -g_u * g_u;
        const float c_l = g_u - m_l * S_u;

        const int row = b * C + i;
        float* __restrict__ lower_coef = out + 2 * BC + (long long)row * C;
        float* __restrict__ upper_coef = out + 2 * BC + BCC + (long long)row * C;

        const float Kl = m_l * e_mi;
        const float dl = -m_l * SA_l;
        const float du = -m_u * SA_u;
        #pragma unroll
        for (int q = 0; q < 4; ++q) {
            const int jb = q * 256 + lane * 4;
            const f32x4 Em4 = *reinterpret_cast<const f32x4*>(&sEm[jb]);
            f32x4 lv, uv;
            #pragma unroll
            for (int k = 0; k < 4; ++k) {
                const int j = jb + k;
                lv[k] = (j == i) ? dl : Kl * Em4[k];
                uv[k] = (j == i) ? du : m_u * a[q * 4 + k];
            }
            *reinterpret_cast<f32x4*>(lower_coef + jb) = lv;
            *reinterpret_cast<f32x4*>(upper_coef + jb) = uv;
        }

        if (lane == 0) {
            out[row]                         = fminf(fmaxf(g_u, 0.f), 1.f); // soft_lower
            out[BC + row]                    = fminf(fmaxf(g_l, 0.f), 1.f); // soft_upper
            out[2 * BC + 2 * BCC + row]      = fmaf(m_l, SB_l, c_l);        // lower bias
            out[2 * BC + 2 * BCC + BC + row] = fmaf(m_u, SB_u, c_u);        // upper bias
        }
    }
}

} // namespace

extern "C" void kernel_launch(void* const* d_in, const int* in_sizes, int n_in,
                              void* d_out, int out_size, void* d_ws, size_t ws_size,
                              hipStream_t stream) {
    const float* lower = (const float*)d_in[0];
    const float* upper = (const float*)d_in[1];
    float* out = (float*)d_out;
    bounded_softmax_kernel<<<dim3(BC / TI), dim3(256), 0, stream>>>(lower, upper, out);
}